// Round 1
// baseline (1296.943 us; speedup 1.0000x reference)
//
#include <hip/hip_runtime.h>

// ---------------------------------------------------------------------------
// Decoder: out = (tanh(x @ (s1*tern(w1-n1)) + b1)) @ (s2*tern(w2-n2)) + b2
// B=4096, D_IN=1024, D_H=16384, D_OUT=3072
//
// Strategy: s1/s2 are per-column -> factor out of GEMM. Ternary {-1,0,1} is
// exact in bf16. Pre-pack x/tern1/tern2 into tile-major [*][*][128][32] bf16
// chunks so GEMM staging is contiguous global_load_lds(16B). m97-style
// 128x128x32 MFMA GEMM (16x16x32_bf16, 4 waves, 4x4 tiles/wave).
// ---------------------------------------------------------------------------

typedef __bf16 bf16x8 __attribute__((ext_vector_type(8)));
typedef float f32x4 __attribute__((ext_vector_type(4)));

#define AS1 __attribute__((address_space(1)))
#define AS3 __attribute__((address_space(3)))

__device__ __forceinline__ void gload_lds16(const void* g, void* l) {
    __builtin_amdgcn_global_load_lds((AS1 const void*)g, (AS3 void*)l, 16, 0, 0);
}

__device__ __forceinline__ unsigned short f2bf(float f) {
    union { float f; unsigned int u; } v; v.f = f;
    unsigned int u = v.u;
    unsigned int r = u + 0x7fffu + ((u >> 16) & 1u);
    return (unsigned short)(r >> 16);
}

// scale arrives as a 1-element array; python int -> int32, but be robust to
// a float32 1.0f as well (bit pattern 0x3f800000 is huge as an int).
__device__ __forceinline__ float load_scale(const void* p) {
    int i = *(const int*)p;
    if (i >= -1000000 && i <= 1000000) return (float)i;
    union { int i; float f; } v; v.i = i; return v.f;
}

// ---------------------------------------------------------------------------
// pack_x: x[M][K] fp32 -> chunks [M/128][K/32][128][32] bf16
// grid (K/32, M/128), block 256
// ---------------------------------------------------------------------------
__global__ __launch_bounds__(256) void pack_x_kernel(
    const float* __restrict__ x, unsigned short* __restrict__ out,
    int K, int Kt)
{
    const int kt = blockIdx.x, mt = blockIdx.y;
    const int tid = threadIdx.x;
    unsigned short* chunk = out + (size_t)(mt * Kt + kt) * 4096;
#pragma unroll
    for (int i = 0; i < 16; i++) {
        int j = tid + i * 256;
        int mi = j >> 5, ki = j & 31;
        chunk[j] = f2bf(x[(size_t)(mt * 128 + mi) * K + kt * 32 + ki]);
    }
}

// ---------------------------------------------------------------------------
// quant_pack_w: w,n [K][N] fp32 -> tern bf16 chunks [N/128][K/32][128][32]
// (transposed to N-major via LDS tile). grid (K/32, N/128), block 256
// ---------------------------------------------------------------------------
__global__ __launch_bounds__(256) void quant_pack_w(
    const float* __restrict__ w, const float* __restrict__ nz,
    const void* __restrict__ scale_ptr,
    unsigned short* __restrict__ out, int N, int Kt)
{
    __shared__ unsigned short lt[128 * 33];
    const int kt = blockIdx.x, nt = blockIdx.y;
    const int tid = threadIdx.x;
    const float scale = load_scale(scale_ptr);
#pragma unroll
    for (int i = 0; i < 16; i++) {
        int s = tid + i * 256;
        int kr = s >> 7, nc = s & 127;          // 32 rows (k) x 128 cols (n)
        size_t g = (size_t)(kt * 32 + kr) * N + nt * 128 + nc;
        float q = w[g] - scale * nz[g];
        unsigned short t = (q > 1.f) ? 0x3F80u : ((q < -1.f) ? 0xBF80u : 0u);
        lt[nc * 33 + kr] = t;
    }
    __syncthreads();
    unsigned short* chunk = out + (size_t)(nt * Kt + kt) * 4096;
#pragma unroll
    for (int i = 0; i < 16; i++) {
        int j = tid + i * 256;
        chunk[j] = lt[(j >> 5) * 33 + (j & 31)];
    }
}

// ---------------------------------------------------------------------------
// GEMM core: C[128m x 128n] tile, BK=32, 4 waves (2x2), each wave 4x4 MFMA
// 16x16x32_bf16 tiles. A chunks [Mt][Kt][128][32], B chunks [Nt][Kt][128][32]
// (B stored n-major, k-contiguous == B^T).
// ---------------------------------------------------------------------------

// GEMM1: h = tanh(s1[n]*acc + b1[n]) written bf16 into GEMM2's packed-A
// layout: [M/128][16384/32][128][32]
__global__ __launch_bounds__(256) void gemm1_kernel(
    const unsigned short* __restrict__ Ap,   // xq
    const unsigned short* __restrict__ Bp,   // w1 tern
    unsigned short* __restrict__ Hq,
    const float* __restrict__ s1, const float* __restrict__ b1,
    int Kt)
{
    __shared__ unsigned short As[4096];
    __shared__ unsigned short Bs[4096];
    const int tid = threadIdx.x;
    const int nt = blockIdx.x, mt = blockIdx.y;
    const int lane = tid & 63, wave = tid >> 6;
    const int wm = (wave >> 1) * 64, wn = (wave & 1) * 64;
    const int l15 = lane & 15, lq = lane >> 4;

    f32x4 acc[4][4] = {};

    const unsigned short* Abase = Ap + (size_t)(mt * Kt) * 4096;
    const unsigned short* Bbase = Bp + (size_t)(nt * Kt) * 4096;

    for (int kt = 0; kt < Kt; ++kt) {
        const unsigned short* Ac = Abase + kt * 4096;
        const unsigned short* Bc = Bbase + kt * 4096;
        gload_lds16(Ac + tid * 8,        &As[tid * 8]);
        gload_lds16(Ac + 2048 + tid * 8, &As[2048 + tid * 8]);
        gload_lds16(Bc + tid * 8,        &Bs[tid * 8]);
        gload_lds16(Bc + 2048 + tid * 8, &Bs[2048 + tid * 8]);
        __syncthreads();

        bf16x8 af[4], bfr[4];
#pragma unroll
        for (int t = 0; t < 4; t++) {
            af[t]  = *(const bf16x8*)(&As[(wm + t * 16 + l15) * 32 + lq * 8]);
            bfr[t] = *(const bf16x8*)(&Bs[(wn + t * 16 + l15) * 32 + lq * 8]);
        }
#pragma unroll
        for (int i = 0; i < 4; i++)
#pragma unroll
            for (int j = 0; j < 4; j++)
                acc[i][j] = __builtin_amdgcn_mfma_f32_16x16x32_bf16(
                    af[i], bfr[j], acc[i][j], 0, 0, 0);
        __syncthreads();
    }

    // epilogue: tanh(s1*acc+b1) -> packed bf16 for GEMM2 (K2t = 512)
#pragma unroll
    for (int i = 0; i < 4; i++) {
#pragma unroll
        for (int j = 0; j < 4; j++) {
            int nl = wn + j * 16 + l15;          // local col 0..127
            int ng = nt * 128 + nl;
            float sc = s1[ng], bb = b1[ng];
#pragma unroll
            for (int r = 0; r < 4; r++) {
                int ml = wm + i * 16 + lq * 4 + r;
                float v = tanhf(sc * acc[i][j][r] + bb);
                size_t off = ((size_t)(mt * 512 + nt * 4 + (nl >> 5)) * 128 + ml) * 32
                             + (nl & 31);
                Hq[off] = f2bf(v);
            }
        }
    }
}

// GEMM2: out[m][n] = s2[n]*acc + b2[n], fp32 row-major [4096][3072]
__global__ __launch_bounds__(256) void gemm2_kernel(
    const unsigned short* __restrict__ Ap,   // hq
    const unsigned short* __restrict__ Bp,   // w2 tern
    float* __restrict__ out,
    const float* __restrict__ s2, const float* __restrict__ b2,
    int Kt)
{
    __shared__ unsigned short As[4096];
    __shared__ unsigned short Bs[4096];
    const int tid = threadIdx.x;
    const int nt = blockIdx.x, mt = blockIdx.y;
    const int lane = tid & 63, wave = tid >> 6;
    const int wm = (wave >> 1) * 64, wn = (wave & 1) * 64;
    const int l15 = lane & 15, lq = lane >> 4;

    f32x4 acc[4][4] = {};

    const unsigned short* Abase = Ap + (size_t)(mt * Kt) * 4096;
    const unsigned short* Bbase = Bp + (size_t)(nt * Kt) * 4096;

    for (int kt = 0; kt < Kt; ++kt) {
        const unsigned short* Ac = Abase + kt * 4096;
        const unsigned short* Bc = Bbase + kt * 4096;
        gload_lds16(Ac + tid * 8,        &As[tid * 8]);
        gload_lds16(Ac + 2048 + tid * 8, &As[2048 + tid * 8]);
        gload_lds16(Bc + tid * 8,        &Bs[tid * 8]);
        gload_lds16(Bc + 2048 + tid * 8, &Bs[2048 + tid * 8]);
        __syncthreads();

        bf16x8 af[4], bfr[4];
#pragma unroll
        for (int t = 0; t < 4; t++) {
            af[t]  = *(const bf16x8*)(&As[(wm + t * 16 + l15) * 32 + lq * 8]);
            bfr[t] = *(const bf16x8*)(&Bs[(wn + t * 16 + l15) * 32 + lq * 8]);
        }
#pragma unroll
        for (int i = 0; i < 4; i++)
#pragma unroll
            for (int j = 0; j < 4; j++)
                acc[i][j] = __builtin_amdgcn_mfma_f32_16x16x32_bf16(
                    af[i], bfr[j], acc[i][j], 0, 0, 0);
        __syncthreads();
    }

#pragma unroll
    for (int i = 0; i < 4; i++) {
#pragma unroll
        for (int j = 0; j < 4; j++) {
            int nl = wn + j * 16 + l15;
            int ng = nt * 128 + nl;
            float sc = s2[ng], bb = b2[ng];
#pragma unroll
            for (int r = 0; r < 4; r++) {
                int ml = wm + i * 16 + lq * 4 + r;
                out[(size_t)(mt * 128 + ml) * 3072 + ng] = sc * acc[i][j][r] + bb;
            }
        }
    }
}

// ---------------------------------------------------------------------------
extern "C" void kernel_launch(void* const* d_in, const int* in_sizes, int n_in,
                              void* d_out, int out_size, void* d_ws, size_t ws_size,
                              hipStream_t stream) {
    const float* x  = (const float*)d_in[0];   // [4096,1024]
    const float* w1 = (const float*)d_in[1];   // [1024,16384]
    const float* s1 = (const float*)d_in[2];   // [16384]
    const float* b1 = (const float*)d_in[3];   // [16384]
    const float* w2 = (const float*)d_in[4];   // [16384,3072]
    const float* s2 = (const float*)d_in[5];   // [3072]
    const float* b2 = (const float*)d_in[6];   // [3072]
    const float* n1 = (const float*)d_in[7];   // [1024,16384]
    const float* n2 = (const float*)d_in[8];   // [16384,3072]
    const void* scale_p = d_in[9];             // scalar
    float* out = (float*)d_out;

    // workspace layout (MiB offsets): xq 8 | w1q 32 | hq 128 | w2q 96 = 264
    if (ws_size < (264ull << 20)) return;
    unsigned char* ws = (unsigned char*)d_ws;
    unsigned short* xq  = (unsigned short*)(ws);
    unsigned short* w1q = (unsigned short*)(ws + (8ull << 20));
    unsigned short* hq  = (unsigned short*)(ws + (40ull << 20));
    unsigned short* w2q = (unsigned short*)(ws + (168ull << 20));

    // pack/quant
    pack_x_kernel<<<dim3(32, 32), 256, 0, stream>>>(x, xq, 1024, 32);
    quant_pack_w<<<dim3(32, 128), 256, 0, stream>>>(w1, n1, scale_p, w1q, 16384, 32);
    quant_pack_w<<<dim3(512, 24), 256, 0, stream>>>(w2, n2, scale_p, w2q, 3072, 512);

    // GEMM1: [4096x1024] @ [1024x16384] -> hq (packed bf16, fused tanh)
    gemm1_kernel<<<dim3(128, 32), 256, 0, stream>>>(xq, w1q, hq, s1, b1, 32);
    // GEMM2: [4096x16384] @ [16384x3072] -> out fp32
    gemm2_kernel<<<dim3(24, 32), 256, 0, stream>>>(hq, w2q, out, s2, b2, 512);
}

// Round 2
// 1176.196 us; speedup vs baseline: 1.1027x; 1.1027x over previous
//
#include <hip/hip_runtime.h>

// ---------------------------------------------------------------------------
// Decoder: out = (tanh(x @ (s1*tern(w1-n1)) + b1)) @ (s2*tern(w2-n2)) + b2
// B=4096, D_IN=1024, D_H=16384, D_OUT=3072
//
// Round-2: fragment-major pack layout (conflict-free ds_read_b128 =
// uniform_base + lane*16), 32x32x16 MFMA (2x2 tiles/wave), vectorized
// quant/pack, fast tanh.
//
// Chunk format (8192 B = one 128(m|n) x 32(k) bf16 tile):
//   elem(s, h, lane, e) = T[m = s*32 + (lane&31)][k = h*16 + (lane>>5)*8 + e]
//   flat elem offset = s*1024 + h*512 + lane*8 + e   (s=0..3, h=0..1)
// This is exactly the 32x32x16 MFMA A/B operand order, so fragment reads are
// ds_read_b128 at subtile_base + lane*16 (zero bank conflicts) and staging is
// global_load_lds(16B) with the required uniform+lane*16 LDS dst.
// ---------------------------------------------------------------------------

typedef __bf16 bf16x8 __attribute__((ext_vector_type(8)));
typedef float f32x16 __attribute__((ext_vector_type(16)));

#define AS1 __attribute__((address_space(1)))
#define AS3 __attribute__((address_space(3)))

__device__ __forceinline__ void gload_lds16(const void* g, void* l) {
    __builtin_amdgcn_global_load_lds((AS1 const void*)g, (AS3 void*)l, 16, 0, 0);
}

__device__ __forceinline__ unsigned short f2bf(float f) {
    union { float f; unsigned int u; } v; v.f = f;
    unsigned int u = v.u;
    unsigned int r = u + 0x7fffu + ((u >> 16) & 1u);
    return (unsigned short)(r >> 16);
}

__device__ __forceinline__ unsigned short tern_bf(float q) {
    return (q > 1.f) ? 0x3F80u : ((q < -1.f) ? 0xBF80u : 0u);
}

// scale arrives as a 1-element array; python int -> int32, but be robust to
// a float32 as well.
__device__ __forceinline__ float load_scale(const void* p) {
    int i = *(const int*)p;
    if (i >= -1000000 && i <= 1000000) return (float)i;
    union { int i; float f; } v; v.i = i; return v.f;
}

__device__ __forceinline__ float tanh_fast(float x) {
    float e = __expf(2.0f * x);                       // v_exp_f32 based
    return 1.0f - 2.0f * __builtin_amdgcn_rcpf(e + 1.0f);
}

// ---------------------------------------------------------------------------
// pack_x: x[4096][1024] fp32 -> chunks [mt=32][kt=32][8192B fragment-major]
// grid (32 kt, 32 mt), block 256. Reads 32B granules (row-scattered, only
// 24 MB total), writes 16B coalesced.
// ---------------------------------------------------------------------------
__global__ __launch_bounds__(256) void pack_x_kernel(
    const float* __restrict__ x, unsigned short* __restrict__ out)
{
    const int kt = blockIdx.x, mt = blockIdx.y, tid = threadIdx.x;
    unsigned short* chunk = out + (size_t)(mt * 32 + kt) * 4096;
#pragma unroll
    for (int it = 0; it < 2; it++) {
        int g = tid + it * 256;
        int s = g >> 7, r = g & 127, h = (r >> 6) & 1, ln = r & 63;
        int m = s * 32 + (ln & 31), k = h * 16 + (ln >> 5) * 8;
        const float* src = x + (size_t)(mt * 128 + m) * 1024 + kt * 32 + k;
        float4 v0 = *(const float4*)src;
        float4 v1 = *(const float4*)(src + 4);
        unsigned int w0 = (unsigned int)f2bf(v0.x) | ((unsigned int)f2bf(v0.y) << 16);
        unsigned int w1 = (unsigned int)f2bf(v0.z) | ((unsigned int)f2bf(v0.w) << 16);
        unsigned int w2 = (unsigned int)f2bf(v1.x) | ((unsigned int)f2bf(v1.y) << 16);
        unsigned int w3 = (unsigned int)f2bf(v1.z) | ((unsigned int)f2bf(v1.w) << 16);
        uint4 o; o.x = w0; o.y = w1; o.z = w2; o.w = w3;
        *(uint4*)&chunk[(size_t)g * 8] = o;
    }
}

// ---------------------------------------------------------------------------
// quant_pack_w: w,n [K][N] fp32 -> tern bf16 chunks [N/128][K/32][8192B]
// float4 coalesced reads, LDS transpose (stride 34: write 4-way, read 2-way
// conflicts), 16B coalesced packed stores. grid (K/32, N/128), block 256
// ---------------------------------------------------------------------------
__global__ __launch_bounds__(256) void quant_pack_w(
    const float* __restrict__ w, const float* __restrict__ nz,
    const void* __restrict__ scale_ptr,
    unsigned short* __restrict__ out, int N, int Kt)
{
    __shared__ unsigned short lt[128 * 34];
    const int kt = blockIdx.x, nt = blockIdx.y, tid = threadIdx.x;
    const float scale = load_scale(scale_ptr);
#pragma unroll
    for (int it = 0; it < 4; it++) {
        int p = it * 1024 + tid * 4;
        int kr = p >> 7, nc = p & 127;
        size_t g = (size_t)(kt * 32 + kr) * N + nt * 128 + nc;
        float4 wv = *(const float4*)(w + g);
        float4 nv = *(const float4*)(nz + g);
        lt[(nc + 0) * 34 + kr] = tern_bf(wv.x - scale * nv.x);
        lt[(nc + 1) * 34 + kr] = tern_bf(wv.y - scale * nv.y);
        lt[(nc + 2) * 34 + kr] = tern_bf(wv.z - scale * nv.z);
        lt[(nc + 3) * 34 + kr] = tern_bf(wv.w - scale * nv.w);
    }
    __syncthreads();
    unsigned short* chunk = out + (size_t)(nt * Kt + kt) * 4096;
#pragma unroll
    for (int it = 0; it < 2; it++) {
        int g = tid + it * 256;
        int s = g >> 7, r = g & 127, h = (r >> 6) & 1, ln = r & 63;
        int n = s * 32 + (ln & 31), k = h * 16 + (ln >> 5) * 8;
        const unsigned int* p32 = (const unsigned int*)&lt[n * 34 + k];
        uint4 o; o.x = p32[0]; o.y = p32[1]; o.z = p32[2]; o.w = p32[3];
        *(uint4*)&chunk[(size_t)g * 8] = o;
    }
}

// ---------------------------------------------------------------------------
// GEMM core: 128x128 tile, BK=32, 4 waves (2x2), each wave 2x2 MFMA
// 32x32x16_bf16 tiles (64x64 per wave).
// ---------------------------------------------------------------------------

// GEMM1: h = tanh(s1[n]*acc + b1[n]) written bf16 into GEMM2's packed-A
// chunks [mt=32][k2t=512][8192B fragment-major]
__global__ __launch_bounds__(256) void gemm1_kernel(
    const unsigned short* __restrict__ Ap,   // xq
    const unsigned short* __restrict__ Bp,   // w1 tern
    unsigned short* __restrict__ Hq,
    const float* __restrict__ s1, const float* __restrict__ b1,
    int Kt)
{
    __shared__ unsigned short As[4096];
    __shared__ unsigned short Bs[4096];
    const int tid = threadIdx.x;
    const int nt = blockIdx.x, mt = blockIdx.y;
    const int lane = tid & 63, wave = tid >> 6;
    const int wm = (wave >> 1) * 64, wn = (wave & 1) * 64;

    f32x16 acc[2][2] = {};

    const unsigned short* Ab = Ap + (size_t)mt * Kt * 4096;
    const unsigned short* Bb = Bp + (size_t)nt * Kt * 4096;

    for (int kt = 0; kt < Kt; ++kt) {
        const unsigned short* Ac = Ab + kt * 4096;
        const unsigned short* Bc = Bb + kt * 4096;
        gload_lds16(Ac + tid * 8,        &As[tid * 8]);
        gload_lds16(Ac + 2048 + tid * 8, &As[2048 + tid * 8]);
        gload_lds16(Bc + tid * 8,        &Bs[tid * 8]);
        gload_lds16(Bc + 2048 + tid * 8, &Bs[2048 + tid * 8]);
        __syncthreads();

        bf16x8 af[2][2], bg[2][2];
#pragma unroll
        for (int h = 0; h < 2; h++)
#pragma unroll
            for (int i = 0; i < 2; i++) {
                af[i][h] = *(const bf16x8*)&As[((wm >> 5) + i) * 1024 + h * 512 + lane * 8];
                bg[i][h] = *(const bf16x8*)&Bs[((wn >> 5) + i) * 1024 + h * 512 + lane * 8];
            }
#pragma unroll
        for (int h = 0; h < 2; h++)
#pragma unroll
            for (int i = 0; i < 2; i++)
#pragma unroll
                for (int j = 0; j < 2; j++)
                    acc[i][j] = __builtin_amdgcn_mfma_f32_32x32x16_bf16(
                        af[i][h], bg[j][h], acc[i][j], 0, 0, 0);
        __syncthreads();
    }

    // epilogue: tanh(s1*acc+b1) -> fragment-major bf16 chunks for GEMM2
    const int l31 = lane & 31;
    const int hsel = (lane >> 4) & 1;      // (k_local>>4)
    const int b32sel = (lane >> 3) & 1;    // which 8-elem group within half
    const int e = lane & 7;
    const int rowbase = 4 * (lane >> 5);
#pragma unroll
    for (int j = 0; j < 2; j++) {
        int k2g = nt * 128 + wn + j * 32 + l31;
        float sc = s1[k2g], bb = b1[k2g];
        size_t ct = (size_t)mt * 512 + nt * 4 + (wn >> 5) + j;
        unsigned short* chunk = Hq + ct * 4096;
#pragma unroll
        for (int i = 0; i < 2; i++) {
            int sbase = ((wm >> 5) + i) * 1024 + hsel * 512 + b32sel * 256 + e;
#pragma unroll
            for (int reg = 0; reg < 16; reg++) {
                int row = (reg & 3) + 8 * (reg >> 2) + rowbase;
                float v = tanh_fast(sc * acc[i][j][reg] + bb);
                chunk[sbase + row * 8] = f2bf(v);
            }
        }
    }
}

// GEMM2: out[m][n] = s2[n]*acc + b2[n], fp32 row-major [4096][3072]
__global__ __launch_bounds__(256) void gemm2_kernel(
    const unsigned short* __restrict__ Ap,   // hq
    const unsigned short* __restrict__ Bp,   // w2 tern
    float* __restrict__ out,
    const float* __restrict__ s2, const float* __restrict__ b2,
    int Kt)
{
    __shared__ unsigned short As[4096];
    __shared__ unsigned short Bs[4096];
    const int tid = threadIdx.x;
    const int nt = blockIdx.x, mt = blockIdx.y;
    const int lane = tid & 63, wave = tid >> 6;
    const int wm = (wave >> 1) * 64, wn = (wave & 1) * 64;

    f32x16 acc[2][2] = {};

    const unsigned short* Ab = Ap + (size_t)mt * Kt * 4096;
    const unsigned short* Bb = Bp + (size_t)nt * Kt * 4096;

    for (int kt = 0; kt < Kt; ++kt) {
        const unsigned short* Ac = Ab + kt * 4096;
        const unsigned short* Bc = Bb + kt * 4096;
        gload_lds16(Ac + tid * 8,        &As[tid * 8]);
        gload_lds16(Ac + 2048 + tid * 8, &As[2048 + tid * 8]);
        gload_lds16(Bc + tid * 8,        &Bs[tid * 8]);
        gload_lds16(Bc + 2048 + tid * 8, &Bs[2048 + tid * 8]);
        __syncthreads();

        bf16x8 af[2][2], bg[2][2];
#pragma unroll
        for (int h = 0; h < 2; h++)
#pragma unroll
            for (int i = 0; i < 2; i++) {
                af[i][h] = *(const bf16x8*)&As[((wm >> 5) + i) * 1024 + h * 512 + lane * 8];
                bg[i][h] = *(const bf16x8*)&Bs[((wn >> 5) + i) * 1024 + h * 512 + lane * 8];
            }
#pragma unroll
        for (int h = 0; h < 2; h++)
#pragma unroll
            for (int i = 0; i < 2; i++)
#pragma unroll
                for (int j = 0; j < 2; j++)
                    acc[i][j] = __builtin_amdgcn_mfma_f32_32x32x16_bf16(
                        af[i][h], bg[j][h], acc[i][j], 0, 0, 0);
        __syncthreads();
    }

    const int l31 = lane & 31;
    const int rowbase = 4 * (lane >> 5);
#pragma unroll
    for (int j = 0; j < 2; j++) {
        int n = nt * 128 + wn + j * 32 + l31;
        float sc = s2[n], bb = b2[n];
#pragma unroll
        for (int i = 0; i < 2; i++) {
#pragma unroll
            for (int reg = 0; reg < 16; reg++) {
                int m = mt * 128 + wm + i * 32 + (reg & 3) + 8 * (reg >> 2) + rowbase;
                out[(size_t)m * 3072 + n] = sc * acc[i][j][reg] + bb;
            }
        }
    }
}

// ---------------------------------------------------------------------------
extern "C" void kernel_launch(void* const* d_in, const int* in_sizes, int n_in,
                              void* d_out, int out_size, void* d_ws, size_t ws_size,
                              hipStream_t stream) {
    const float* x  = (const float*)d_in[0];   // [4096,1024]
    const float* w1 = (const float*)d_in[1];   // [1024,16384]
    const float* s1 = (const float*)d_in[2];   // [16384]
    const float* b1 = (const float*)d_in[3];   // [16384]
    const float* w2 = (const float*)d_in[4];   // [16384,3072]
    const float* s2 = (const float*)d_in[5];   // [3072]
    const float* b2 = (const float*)d_in[6];   // [3072]
    const float* n1 = (const float*)d_in[7];   // [1024,16384]
    const float* n2 = (const float*)d_in[8];   // [16384,3072]
    const void* scale_p = d_in[9];             // scalar
    float* out = (float*)d_out;

    // workspace layout (MiB offsets): xq 8 | w1q 32 | hq 128 | w2q 96 = 264
    if (ws_size < (264ull << 20)) return;
    unsigned char* ws = (unsigned char*)d_ws;
    unsigned short* xq  = (unsigned short*)(ws);
    unsigned short* w1q = (unsigned short*)(ws + (8ull << 20));
    unsigned short* hq  = (unsigned short*)(ws + (40ull << 20));
    unsigned short* w2q = (unsigned short*)(ws + (168ull << 20));

    // pack/quant
    pack_x_kernel<<<dim3(32, 32), 256, 0, stream>>>(x, xq);
    quant_pack_w<<<dim3(32, 128), 256, 0, stream>>>(w1, n1, scale_p, w1q, 16384, 32);
    quant_pack_w<<<dim3(512, 24), 256, 0, stream>>>(w2, n2, scale_p, w2q, 3072, 512);

    // GEMM1: [4096x1024] @ [1024x16384] -> hq (packed bf16, fused tanh)
    gemm1_kernel<<<dim3(128, 32), 256, 0, stream>>>(xq, w1q, hq, s1, b1, 32);
    // GEMM2: [4096x16384] @ [16384x3072] -> out fp32
    gemm2_kernel<<<dim3(24, 32), 256, 0, stream>>>(hq, w2q, out, s2, b2, 512);
}